// Round 14
// baseline (149.407 us; speedup 1.0000x reference)
//
#include <hip/hip_runtime.h>
#include <math.h>

#define B_N 8192
#define D_N 512
#define S_N 5
#define C_N 2048
#define H_N 4

typedef __attribute__((ext_vector_type(8))) short bf16x8;
typedef __attribute__((ext_vector_type(4))) float floatx4;

__device__ __forceinline__ float bf2f(short u) {
  union { unsigned int i; float f; } c;
  c.i = ((unsigned int)(unsigned short)u) << 16;
  return c.f;
}
__device__ __forceinline__ short f2bf(float f) {
  union { float f; unsigned int i; } c; c.f = f;
  unsigned int x = c.i;
  x += 0x7fffu + ((x >> 16) & 1u);   // round-to-nearest-even
  return (short)(x >> 16);
}
__device__ __forceinline__ unsigned long long pack4(float a, float b, float c, float d) {
  return (unsigned long long)(unsigned short)f2bf(a)
       | ((unsigned long long)(unsigned short)f2bf(b) << 16)
       | ((unsigned long long)(unsigned short)f2bf(c) << 32)
       | ((unsigned long long)(unsigned short)f2bf(d) << 48);
}

// ---------------- prep: f->bf16 cvt + WqT transpose + Wk->bf16 (R8 verbatim, passed) ----
__global__ __launch_bounds__(256) void k_prep(
    const float* __restrict__ f, const float* __restrict__ Wq,
    const float* __restrict__ Wk, short* __restrict__ fbf,
    short* __restrict__ WqT, short* __restrict__ Wkb) {
  __shared__ float lds[64][65];
  const int bx = blockIdx.x, t = threadIdx.x;
  if (bx < 2048) {
    int i = bx * 256 + t;
    const floatx4* p = (const floatx4*)(f + (size_t)i * 8);
    floatx4 a = p[0], b = p[1];
    *(unsigned long long*)(fbf + (size_t)i * 8)     = pack4(a[0], a[1], a[2], a[3]);
    *(unsigned long long*)(fbf + (size_t)i * 8 + 4) = pack4(b[0], b[1], b[2], b[3]);
  } else if (bx < 2112) {
    const int bb = bx - 2048;
    const int r0 = (bb >> 3) * 64, c0 = (bb & 7) * 64;
#pragma unroll
    for (int i = 0; i < 16; ++i) {
      int r = i * 4 + (t >> 6), c = t & 63;
      lds[r][c] = Wq[(size_t)(r0 + r) * 512 + c0 + c];
    }
    __syncthreads();
#pragma unroll
    for (int i = 0; i < 16; ++i) {
      int cL = i * 4 + (t >> 6), rL = t & 63;
      WqT[(size_t)(c0 + cL) * 512 + r0 + rL] = f2bf(lds[rL][cL]);
    }
  } else {
    const int base = (bx - 2112) * 8192 + t * 4;
#pragma unroll
    for (int i = 0; i < 8; ++i) {
      int idx = base + i * 1024;
      floatx4 v = *(const floatx4*)(Wk + idx);
      *(unsigned long long*)(Wkb + idx) = pack4(v[0], v[1], v[2], v[3]);
    }
  }
}

__device__ __forceinline__ void gll(const short* g, short* l) {
  __builtin_amdgcn_global_load_lds(
      (const __attribute__((address_space(1))) unsigned int*)(g),
      (__attribute__((address_space(3))) unsigned int*)(l), 16, 0, 0);
}

// ---------------- gemmQR: merged Q-GEMM (K=512) + qt epilogue + R-GEMM from LDS --------
// R13 verbatim (passed) + XCD-aware bijective swizzle: grid is 1-D 512 = 8 XCDs x 64;
// swz = (id&7)*64 + id>>3 puts all 4 head-blocks of a row-tile on ONE XCD so the shared
// fbf A-panel is fetched into that XCD's L2 once (T1; scheduling-only, bit-identical).
__global__ __launch_bounds__(256) void k_gemmQR(
    const short* __restrict__ A,            // fbf [8192][512]
    const short* __restrict__ BT,           // WqT [512][512]
    const short* __restrict__ Wkb,          // [512][512] (a-major)
    short* __restrict__ Rbf,                // [8192][2048]
    const float* __restrict__ bias,         // bq
    float* __restrict__ qtp, const float* __restrict__ bkp) {
  __shared__ __align__(16) short As[2][2048];
  __shared__ __align__(16) short Bs[2][4096];
  __shared__ __align__(16) short Qt[64][132];   // padded bf16 Q-tile
  __shared__ float qtLds[64][2];

  const int tid = threadIdx.x;
  const int lane = tid & 63;
  const int wid = tid >> 6;
  const int wr = wid >> 1, wc = wid & 1;
  const int id = blockIdx.x;
  const int swz = (id & 7) * 64 + (id >> 3);    // bijective on [0,512)
  const int h = swz & 3;
  const int row0 = (swz >> 2) * 64;
  const int col0 = h * 128;

  const int r1 = tid >> 2, hk = tid & 3;
  const short* Ag1 = A + (size_t)(row0 + r1) * 512 + hk * 8;
  const short* Bg1 = BT + (size_t)(col0 + r1) * 512 + hk * 8;
  const short* Bg2 = BT + (size_t)(col0 + 64 + r1) * 512 + hk * 8;

  floatx4 acc[2][4];
  const floatx4 zero = {0.0f, 0.0f, 0.0f, 0.0f};
#pragma unroll
  for (int m = 0; m < 2; ++m)
#pragma unroll
    for (int n = 0; n < 4; ++n) acc[m][n] = zero;

  int cur = 0;
  auto stage = [&](int q, int kb) {
    gll(Ag1 + kb, &As[q][tid * 8]);
    gll(Bg1 + kb, &Bs[q][tid * 8]);
    gll(Bg2 + kb, &Bs[q][tid * 8 + 2048]);
  };

  stage(0, 0);
  __syncthreads();

  for (int t = 0; t < 16; ++t) {          // K=512
    if (t + 1 < 16) stage(cur ^ 1, (t + 1) * 32);
    bf16x8 af[2], bfr[4];
#pragma unroll
    for (int m = 0; m < 2; ++m)
      af[m] = *(const bf16x8*)&As[cur][(wr * 32 + m * 16 + (lane & 15)) * 32 + (lane >> 4) * 8];
#pragma unroll
    for (int n = 0; n < 4; ++n)
      bfr[n] = *(const bf16x8*)&Bs[cur][(wc * 64 + n * 16 + (lane & 15)) * 32 + (lane >> 4) * 8];
#pragma unroll
    for (int m = 0; m < 2; ++m)
#pragma unroll
      for (int n = 0; n < 4; ++n)
        acc[m][n] = __builtin_amdgcn_mfma_f32_16x16x32_bf16(af[m], bfr[n], acc[m][n], 0, 0, 0);
    __syncthreads();
    cur ^= 1;
  }

  // ---- epilogue A: bias, qt partials, Q -> LDS Qt ----
  float qp[2][4] = {{0, 0, 0, 0}, {0, 0, 0, 0}};
#pragma unroll
  for (int m = 0; m < 2; ++m) {
    int lrow0 = wr * 32 + m * 16 + (lane >> 4) * 4;
#pragma unroll
    for (int n = 0; n < 4; ++n) {
      int lc = wc * 64 + n * 16 + (lane & 15);     // local col within head
      float bv = bias[col0 + lc];
      float bkv = bkp[col0 + lc];
#pragma unroll
      for (int j = 0; j < 4; ++j) {
        float q = acc[m][n][j] + bv;
        Qt[lrow0 + j][lc] = f2bf(q);
        qp[m][j] += q * bkv;
      }
    }
  }

#pragma unroll
  for (int m = 0; m < 2; ++m)
#pragma unroll
    for (int j = 0; j < 4; ++j) {
      float p = qp[m][j];
      p += __shfl_xor(p, 1, 64);
      p += __shfl_xor(p, 2, 64);
      p += __shfl_xor(p, 4, 64);
      p += __shfl_xor(p, 8, 64);
      int lrow = wr * 32 + m * 16 + (lane >> 4) * 4 + j;
      if ((lane & 15) == 0) qtLds[lrow][wc] = p;
    }
  __syncthreads();                        // Qt + qtLds visible
  if (tid < 64)
    qtp[(size_t)(row0 + tid) * H_N + h] = qtLds[tid][0] + qtLds[tid][1];

  // ---- phase B: R chunk-by-chunk; A from Qt (LDS), B from Wkb (L2) ----
  for (int cc = 0; cc < 4; ++cc) {
    floatx4 acc2[2][4];
#pragma unroll
    for (int m = 0; m < 2; ++m)
#pragma unroll
      for (int n = 0; n < 4; ++n) acc2[m][n] = zero;

#pragma unroll
    for (int ks = 0; ks < 4; ++ks) {      // K=128 (head-local j)
      bf16x8 af[2], bfr[4];
#pragma unroll
      for (int m = 0; m < 2; ++m)
        af[m] = *(const bf16x8*)&Qt[wr * 32 + m * 16 + (lane & 15)][ks * 32 + (lane >> 4) * 8];
#pragma unroll
      for (int n = 0; n < 4; ++n) {
        int a = cc * 128 + wc * 64 + n * 16 + (lane & 15);
        bfr[n] = *(const bf16x8*)(Wkb + (size_t)a * 512 + col0 + ks * 32 + (lane >> 4) * 8);
      }
#pragma unroll
      for (int m = 0; m < 2; ++m)
#pragma unroll
        for (int n = 0; n < 4; ++n)
          acc2[m][n] = __builtin_amdgcn_mfma_f32_16x16x32_bf16(af[m], bfr[n], acc2[m][n], 0, 0, 0);
    }

#pragma unroll
    for (int m = 0; m < 2; ++m) {
      int rowb = row0 + wr * 32 + m * 16 + (lane >> 4) * 4;
#pragma unroll
      for (int n = 0; n < 4; ++n) {
        int ocol = h * 512 + cc * 128 + wc * 64 + n * 16 + (lane & 15);
#pragma unroll
        for (int j = 0; j < 4; ++j)
          Rbf[(size_t)(rowb + j) * 2048 + ocol] = f2bf(acc2[m][n][j]);
      }
    }
  }
}

// ---------------- fused stats + attention + logits mix (R9 verbatim, passed) -----------
__global__ __launch_bounds__(256, 4) void k_fused(
    const float* __restrict__ f, const float* __restrict__ sf,
    const float* __restrict__ emb, const float* __restrict__ qt,
    const short* __restrict__ Rbf, const float* __restrict__ temp,
    const float* __restrict__ attn_w, const float* __restrict__ logits,
    float* __restrict__ out, float* __restrict__ comb_out) {
  const int lane = threadIdx.x & 63;
  const int wid = threadIdx.x >> 6;
  const int b = blockIdx.x * 4 + wid;
  const int a0 = lane * 8;

  const floatx4* fp = (const floatx4*)(f + (size_t)b * D_N + a0);
  floatx4 fA = fp[0], fB = fp[1];
  float fv[8];
#pragma unroll
  for (int j = 0; j < 4; ++j) { fv[j] = fA[j]; fv[4 + j] = fB[j]; }
  float ffp = 0;
#pragma unroll
  for (int j = 0; j < 8; ++j) ffp += fv[j] * fv[j];

  const floatx4 qtv = *(const floatx4*)(qt + (size_t)b * H_N);

  bf16x8 rv[H_N];
#pragma unroll
  for (int h = 0; h < H_N; ++h)
    rv[h] = *(const bf16x8*)(Rbf + (size_t)b * 2048 + h * 512 + a0);

  float fs_[S_N], ss_[S_N], sc_[S_N][H_N];

#pragma unroll
  for (int s = 0; s < S_N; ++s) {
    const floatx4* sp = (const floatx4*)(sf + ((size_t)s * B_N + b) * D_N + a0);
    floatx4 sA = sp[0], sB = sp[1];
    const floatx4* ep = (const floatx4*)(emb + (size_t)s * D_N + a0);
    floatx4 eA = ep[0], eB = ep[1];
    float sv[8], se[8];
#pragma unroll
    for (int j = 0; j < 4; ++j) {
      sv[j] = sA[j]; sv[4 + j] = sB[j];
      se[j] = sA[j] + eA[j]; se[4 + j] = sB[j] + eB[j];
    }
    float fsp = 0, ssp = 0;
    float scp[H_N] = {0, 0, 0, 0};
#pragma unroll
    for (int j = 0; j < 8; ++j) {
      fsp += fv[j] * sv[j];
      ssp += sv[j] * sv[j];
#pragma unroll
      for (int h = 0; h < H_N; ++h) scp[h] += se[j] * bf2f(rv[h][j]);
    }
    fs_[s] = fsp; ss_[s] = ssp;
#pragma unroll
    for (int h = 0; h < H_N; ++h) sc_[s][h] = scp[h];
  }

  float ffv = ffp;
#pragma unroll
  for (int o = 1; o < 64; o <<= 1) {
    ffv += __shfl_xor(ffv, o, 64);
#pragma unroll
    for (int s = 0; s < S_N; ++s) {
      fs_[s] += __shfl_xor(fs_[s], o, 64);
      ss_[s] += __shfl_xor(ss_[s], o, 64);
#pragma unroll
      for (int h = 0; h < H_N; ++h) sc_[s][h] += __shfl_xor(sc_[s][h], o, 64);
    }
  }

  const float t = fabsf(temp[0]);

  float amha[S_N] = {0, 0, 0, 0, 0};
  const float inv_mha = 1.0f / (sqrtf(128.0f) * t);
#pragma unroll
  for (int h = 0; h < H_N; ++h) {
    float lg[S_N];
#pragma unroll
    for (int s = 0; s < S_N; ++s) lg[s] = (sc_[s][h] + qtv[h]) * inv_mha;
    float mx = lg[0];
#pragma unroll
    for (int s = 1; s < S_N; ++s) mx = fmaxf(mx, lg[s]);
    float e[S_N], sum = 0;
#pragma unroll
    for (int s = 0; s < S_N; ++s) { e[s] = __expf(lg[s] - mx); sum += e[s]; }
    float isum = 0.25f / sum;
#pragma unroll
    for (int s = 0; s < S_N; ++s) amha[s] += e[s] * isum;
  }

  float ageo[S_N];
  {
    const float nf = fmaxf(sqrtf(ffv), 1e-12f);
    float g[S_N];
#pragma unroll
    for (int s = 0; s < S_N; ++s) {
      float ns = fmaxf(sqrtf(ss_[s]), 1e-12f);
      float cs0 = fs_[s] / (nf * ns);
      cs0 = fminf(fmaxf(cs0, -1.0f + 1e-7f), 1.0f - 1e-7f);
      g[s] = __expf(-acosf(cs0) / t);
    }
    float mx = g[0];
#pragma unroll
    for (int s = 1; s < S_N; ++s) mx = fmaxf(mx, g[s]);
    float sum = 0;
#pragma unroll
    for (int s = 0; s < S_N; ++s) { ageo[s] = __expf(g[s] - mx); sum += ageo[s]; }
#pragma unroll
    for (int s = 0; s < S_N; ++s) ageo[s] /= sum;
  }

  float acay[S_N];
  {
    const float SQ2 = 1.41421356237309515f;
    const float Aff = 0.72f;
    const float Ass = 0.72f - 0.32f * SQ2;
    const float Afs = -(8.0f + 4.0f * SQ2) / 25.0f;
    float lg[S_N];
#pragma unroll
    for (int s = 0; s < S_N; ++s)
      lg[s] = (Aff * ffv + Ass * ss_[s] + Afs * fs_[s]) / t;
    float mx = lg[0];
#pragma unroll
    for (int s = 1; s < S_N; ++s) mx = fmaxf(mx, lg[s]);
    float sum = 0;
#pragma unroll
    for (int s = 0; s < S_N; ++s) { acay[s] = __expf(lg[s] - mx); sum += acay[s]; }
#pragma unroll
    for (int s = 0; s < S_N; ++s) acay[s] /= sum;
  }

  float w0 = attn_w[0], w1 = attn_w[1], w2 = attn_w[2];
  float wm = fmaxf(w0, fmaxf(w1, w2));
  float e0 = __expf(w0 - wm), e1 = __expf(w1 - wm), e2 = __expf(w2 - wm);
  float wsum = e0 + e1 + e2;
  w0 = e0 / wsum; w1 = e1 / wsum; w2 = e2 / wsum;

  float cb[S_N], csum = 0;
#pragma unroll
  for (int s = 0; s < S_N; ++s) {
    cb[s] = w0 * amha[s] + w1 * ageo[s] + w2 * acay[s];
    csum += cb[s];
  }
  float ic = 1.0f / csum;
  float cbn[S_N];
#pragma unroll
  for (int s = 0; s < S_N; ++s) cbn[s] = cb[s] * ic;
  if (lane == 0) {
#pragma unroll
    for (int s = 0; s < S_N; ++s) comb_out[(size_t)b * S_N + s] = cbn[s];
  }

  const floatx4 fz = {0.f, 0.f, 0.f, 0.f};
#pragma unroll
  for (int cj = 0; cj < 4; ++cj) {
    const int c0 = cj * 512 + lane * 8;
    floatx4 accA = fz, accB = fz;
#pragma unroll
    for (int s = 0; s < S_N; ++s) {
      const float* lp = logits + ((size_t)s * B_N + b) * C_N + c0;
      floatx4 lA = *(const floatx4*)lp;
      floatx4 lB = *(const floatx4*)(lp + 4);
      accA += lA * cbn[s];
      accB += lB * cbn[s];
    }
    float* op = out + (size_t)b * C_N + c0;
    *(floatx4*)op = accA;
    *(floatx4*)(op + 4) = accB;
  }
}

extern "C" void kernel_launch(void* const* d_in, const int* in_sizes, int n_in,
                              void* d_out, int out_size, void* d_ws, size_t ws_size,
                              hipStream_t stream) {
  const float* features = (const float*)d_in[0];
  const float* logits   = (const float*)d_in[1];
  const float* sf       = (const float*)d_in[2];
  const float* Wq       = (const float*)d_in[3];
  const float* bq       = (const float*)d_in[4];
  const float* Wk       = (const float*)d_in[5];
  const float* bk       = (const float*)d_in[6];
  const float* emb      = (const float*)d_in[9];
  const float* temp     = (const float*)d_in[10];
  const float* attn_w   = (const float*)d_in[11];

  float* out  = (float*)d_out;
  float* comb = out + (size_t)B_N * C_N;

  char* w = (char*)d_ws;
  short* fbf = (short*)(w);                    // 8192*512  bf16 =  8.39 MB
  short* Rbf = (short*)(w + 16777216);         // 8192*2048 bf16 = 33.55 MB
  short* WqT = (short*)(w + 50331648);         // 512*512   bf16 =  0.52 MB
  short* Wkb = (short*)(w + 50855936);         // 512*512   bf16 =  0.52 MB
  float* qtb = (float*)(w + 51380224);         // 8192*4    f32

  // 1. f->bf16 + WqT transpose + Wk->bf16
  k_prep<<<dim3(2144), dim3(256), 0, stream>>>(features, Wq, Wk, fbf, WqT, Wkb);
  // 2. merged Q+R GEMM, XCD-swizzled so row-tile quads share one XCD's L2
  k_gemmQR<<<dim3(512), dim3(256), 0, stream>>>(fbf, WqT, Wkb, Rbf, bq, qtb, bk);
  // 3. fused stats + attentions + fuse + logits mix
  k_fused<<<dim3(2048), dim3(256), 0, stream>>>(features, sf, emb, qtb, Rbf,
                                                temp, attn_w, logits, out, comb);
}

// Round 15
// 148.181 us; speedup vs baseline: 1.0083x; 1.0083x over previous
//
#include <hip/hip_runtime.h>
#include <math.h>

#define B_N 8192
#define D_N 512
#define S_N 5
#define C_N 2048
#define H_N 4

typedef __attribute__((ext_vector_type(8))) short bf16x8;
typedef __attribute__((ext_vector_type(4))) float floatx4;

__device__ __forceinline__ float bf2f(short u) {
  union { unsigned int i; float f; } c;
  c.i = ((unsigned int)(unsigned short)u) << 16;
  return c.f;
}
__device__ __forceinline__ short f2bf(float f) {
  union { float f; unsigned int i; } c; c.f = f;
  unsigned int x = c.i;
  x += 0x7fffu + ((x >> 16) & 1u);   // round-to-nearest-even
  return (short)(x >> 16);
}
__device__ __forceinline__ unsigned long long pack4(float a, float b, float c, float d) {
  return (unsigned long long)(unsigned short)f2bf(a)
       | ((unsigned long long)(unsigned short)f2bf(b) << 16)
       | ((unsigned long long)(unsigned short)f2bf(c) << 32)
       | ((unsigned long long)(unsigned short)f2bf(d) << 48);
}

// ---------------- prep: f->bf16 cvt + WqT transpose + Wk->bf16 (R8 verbatim, passed) ----
__global__ __launch_bounds__(256) void k_prep(
    const float* __restrict__ f, const float* __restrict__ Wq,
    const float* __restrict__ Wk, short* __restrict__ fbf,
    short* __restrict__ WqT, short* __restrict__ Wkb) {
  __shared__ float lds[64][65];
  const int bx = blockIdx.x, t = threadIdx.x;
  if (bx < 2048) {
    int i = bx * 256 + t;
    const floatx4* p = (const floatx4*)(f + (size_t)i * 8);
    floatx4 a = p[0], b = p[1];
    *(unsigned long long*)(fbf + (size_t)i * 8)     = pack4(a[0], a[1], a[2], a[3]);
    *(unsigned long long*)(fbf + (size_t)i * 8 + 4) = pack4(b[0], b[1], b[2], b[3]);
  } else if (bx < 2112) {
    const int bb = bx - 2048;
    const int r0 = (bb >> 3) * 64, c0 = (bb & 7) * 64;
#pragma unroll
    for (int i = 0; i < 16; ++i) {
      int r = i * 4 + (t >> 6), c = t & 63;
      lds[r][c] = Wq[(size_t)(r0 + r) * 512 + c0 + c];
    }
    __syncthreads();
#pragma unroll
    for (int i = 0; i < 16; ++i) {
      int cL = i * 4 + (t >> 6), rL = t & 63;
      WqT[(size_t)(c0 + cL) * 512 + r0 + rL] = f2bf(lds[rL][cL]);
    }
  } else {
    const int base = (bx - 2112) * 8192 + t * 4;
#pragma unroll
    for (int i = 0; i < 8; ++i) {
      int idx = base + i * 1024;
      floatx4 v = *(const floatx4*)(Wk + idx);
      *(unsigned long long*)(Wkb + idx) = pack4(v[0], v[1], v[2], v[3]);
    }
  }
}

__device__ __forceinline__ void gll(const short* g, short* l) {
  __builtin_amdgcn_global_load_lds(
      (const __attribute__((address_space(1))) unsigned int*)(g),
      (__attribute__((address_space(3))) unsigned int*)(l), 16, 0, 0);
}

// ---------------- gemmQR: merged Q-GEMM (K=512) + qt epilogue + R-GEMM from LDS --------
// R13 verbatim (passed, 146.3 us best). grid (4 heads, 128 row-tiles).
__global__ __launch_bounds__(256) void k_gemmQR(
    const short* __restrict__ A,            // fbf [8192][512]
    const short* __restrict__ BT,           // WqT [512][512]
    const short* __restrict__ Wkb,          // [512][512] (a-major)
    short* __restrict__ Rbf,                // [8192][2048]
    const float* __restrict__ bias,         // bq
    float* __restrict__ qtp, const float* __restrict__ bkp) {
  __shared__ __align__(16) short As[2][2048];
  __shared__ __align__(16) short Bs[2][4096];
  __shared__ __align__(16) short Qt[64][132];   // padded bf16 Q-tile
  __shared__ float qtLds[64][2];

  const int tid = threadIdx.x;
  const int lane = tid & 63;
  const int wid = tid >> 6;
  const int wr = wid >> 1, wc = wid & 1;
  const int h = blockIdx.x;
  const int row0 = blockIdx.y * 64;
  const int col0 = h * 128;

  const int r1 = tid >> 2, hk = tid & 3;
  const short* Ag1 = A + (size_t)(row0 + r1) * 512 + hk * 8;
  const short* Bg1 = BT + (size_t)(col0 + r1) * 512 + hk * 8;
  const short* Bg2 = BT + (size_t)(col0 + 64 + r1) * 512 + hk * 8;

  floatx4 acc[2][4];
  const floatx4 zero = {0.0f, 0.0f, 0.0f, 0.0f};
#pragma unroll
  for (int m = 0; m < 2; ++m)
#pragma unroll
    for (int n = 0; n < 4; ++n) acc[m][n] = zero;

  int cur = 0;
  auto stage = [&](int q, int kb) {
    gll(Ag1 + kb, &As[q][tid * 8]);
    gll(Bg1 + kb, &Bs[q][tid * 8]);
    gll(Bg2 + kb, &Bs[q][tid * 8 + 2048]);
  };

  stage(0, 0);
  __syncthreads();

  for (int t = 0; t < 16; ++t) {          // K=512
    if (t + 1 < 16) stage(cur ^ 1, (t + 1) * 32);
    bf16x8 af[2], bfr[4];
#pragma unroll
    for (int m = 0; m < 2; ++m)
      af[m] = *(const bf16x8*)&As[cur][(wr * 32 + m * 16 + (lane & 15)) * 32 + (lane >> 4) * 8];
#pragma unroll
    for (int n = 0; n < 4; ++n)
      bfr[n] = *(const bf16x8*)&Bs[cur][(wc * 64 + n * 16 + (lane & 15)) * 32 + (lane >> 4) * 8];
#pragma unroll
    for (int m = 0; m < 2; ++m)
#pragma unroll
      for (int n = 0; n < 4; ++n)
        acc[m][n] = __builtin_amdgcn_mfma_f32_16x16x32_bf16(af[m], bfr[n], acc[m][n], 0, 0, 0);
    __syncthreads();
    cur ^= 1;
  }

  // ---- epilogue A: bias, qt partials, Q -> LDS Qt ----
  float qp[2][4] = {{0, 0, 0, 0}, {0, 0, 0, 0}};
#pragma unroll
  for (int m = 0; m < 2; ++m) {
    int lrow0 = wr * 32 + m * 16 + (lane >> 4) * 4;
#pragma unroll
    for (int n = 0; n < 4; ++n) {
      int lc = wc * 64 + n * 16 + (lane & 15);     // local col within head
      float bv = bias[col0 + lc];
      float bkv = bkp[col0 + lc];
#pragma unroll
      for (int j = 0; j < 4; ++j) {
        float q = acc[m][n][j] + bv;
        Qt[lrow0 + j][lc] = f2bf(q);
        qp[m][j] += q * bkv;
      }
    }
  }

#pragma unroll
  for (int m = 0; m < 2; ++m)
#pragma unroll
    for (int j = 0; j < 4; ++j) {
      float p = qp[m][j];
      p += __shfl_xor(p, 1, 64);
      p += __shfl_xor(p, 2, 64);
      p += __shfl_xor(p, 4, 64);
      p += __shfl_xor(p, 8, 64);
      int lrow = wr * 32 + m * 16 + (lane >> 4) * 4 + j;
      if ((lane & 15) == 0) qtLds[lrow][wc] = p;
    }
  __syncthreads();                        // Qt + qtLds visible
  if (tid < 64)
    qtp[(size_t)(row0 + tid) * H_N + h] = qtLds[tid][0] + qtLds[tid][1];

  // ---- phase B: R chunk-by-chunk; A from Qt (LDS), B from Wkb (L2) ----
  for (int cc = 0; cc < 4; ++cc) {
    floatx4 acc2[2][4];
#pragma unroll
    for (int m = 0; m < 2; ++m)
#pragma unroll
      for (int n = 0; n < 4; ++n) acc2[m][n] = zero;

#pragma unroll
    for (int ks = 0; ks < 4; ++ks) {      // K=128 (head-local j)
      bf16x8 af[2], bfr[4];
#pragma unroll
      for (int m = 0; m < 2; ++m)
        af[m] = *(const bf16x8*)&Qt[wr * 32 + m * 16 + (lane & 15)][ks * 32 + (lane >> 4) * 8];
#pragma unroll
      for (int n = 0; n < 4; ++n) {
        int a = cc * 128 + wc * 64 + n * 16 + (lane & 15);
        bfr[n] = *(const bf16x8*)(Wkb + (size_t)a * 512 + col0 + ks * 32 + (lane >> 4) * 8);
      }
#pragma unroll
      for (int m = 0; m < 2; ++m)
#pragma unroll
        for (int n = 0; n < 4; ++n)
          acc2[m][n] = __builtin_amdgcn_mfma_f32_16x16x32_bf16(af[m], bfr[n], acc2[m][n], 0, 0, 0);
    }

#pragma unroll
    for (int m = 0; m < 2; ++m) {
      int rowb = row0 + wr * 32 + m * 16 + (lane >> 4) * 4;
#pragma unroll
      for (int n = 0; n < 4; ++n) {
        int ocol = h * 512 + cc * 128 + wc * 64 + n * 16 + (lane & 15);
#pragma unroll
        for (int j = 0; j < 4; ++j)
          Rbf[(size_t)(rowb + j) * 2048 + ocol] = f2bf(acc2[m][n][j]);
      }
    }
  }
}

// ---------------- fused stats + attention + logits mix (R9 verbatim, passed) -----------
__global__ __launch_bounds__(256, 4) void k_fused(
    const float* __restrict__ f, const float* __restrict__ sf,
    const float* __restrict__ emb, const float* __restrict__ qt,
    const short* __restrict__ Rbf, const float* __restrict__ temp,
    const float* __restrict__ attn_w, const float* __restrict__ logits,
    float* __restrict__ out, float* __restrict__ comb_out) {
  const int lane = threadIdx.x & 63;
  const int wid = threadIdx.x >> 6;
  const int b = blockIdx.x * 4 + wid;
  const int a0 = lane * 8;

  const floatx4* fp = (const floatx4*)(f + (size_t)b * D_N + a0);
  floatx4 fA = fp[0], fB = fp[1];
  float fv[8];
#pragma unroll
  for (int j = 0; j < 4; ++j) { fv[j] = fA[j]; fv[4 + j] = fB[j]; }
  float ffp = 0;
#pragma unroll
  for (int j = 0; j < 8; ++j) ffp += fv[j] * fv[j];

  const floatx4 qtv = *(const floatx4*)(qt + (size_t)b * H_N);

  bf16x8 rv[H_N];
#pragma unroll
  for (int h = 0; h < H_N; ++h)
    rv[h] = *(const bf16x8*)(Rbf + (size_t)b * 2048 + h * 512 + a0);

  float fs_[S_N], ss_[S_N], sc_[S_N][H_N];

#pragma unroll
  for (int s = 0; s < S_N; ++s) {
    const floatx4* sp = (const floatx4*)(sf + ((size_t)s * B_N + b) * D_N + a0);
    floatx4 sA = sp[0], sB = sp[1];
    const floatx4* ep = (const floatx4*)(emb + (size_t)s * D_N + a0);
    floatx4 eA = ep[0], eB = ep[1];
    float sv[8], se[8];
#pragma unroll
    for (int j = 0; j < 4; ++j) {
      sv[j] = sA[j]; sv[4 + j] = sB[j];
      se[j] = sA[j] + eA[j]; se[4 + j] = sB[j] + eB[j];
    }
    float fsp = 0, ssp = 0;
    float scp[H_N] = {0, 0, 0, 0};
#pragma unroll
    for (int j = 0; j < 8; ++j) {
      fsp += fv[j] * sv[j];
      ssp += sv[j] * sv[j];
#pragma unroll
      for (int h = 0; h < H_N; ++h) scp[h] += se[j] * bf2f(rv[h][j]);
    }
    fs_[s] = fsp; ss_[s] = ssp;
#pragma unroll
    for (int h = 0; h < H_N; ++h) sc_[s][h] = scp[h];
  }

  float ffv = ffp;
#pragma unroll
  for (int o = 1; o < 64; o <<= 1) {
    ffv += __shfl_xor(ffv, o, 64);
#pragma unroll
    for (int s = 0; s < S_N; ++s) {
      fs_[s] += __shfl_xor(fs_[s], o, 64);
      ss_[s] += __shfl_xor(ss_[s], o, 64);
#pragma unroll
      for (int h = 0; h < H_N; ++h) sc_[s][h] += __shfl_xor(sc_[s][h], o, 64);
    }
  }

  const float t = fabsf(temp[0]);

  float amha[S_N] = {0, 0, 0, 0, 0};
  const float inv_mha = 1.0f / (sqrtf(128.0f) * t);
#pragma unroll
  for (int h = 0; h < H_N; ++h) {
    float lg[S_N];
#pragma unroll
    for (int s = 0; s < S_N; ++s) lg[s] = (sc_[s][h] + qtv[h]) * inv_mha;
    float mx = lg[0];
#pragma unroll
    for (int s = 1; s < S_N; ++s) mx = fmaxf(mx, lg[s]);
    float e[S_N], sum = 0;
#pragma unroll
    for (int s = 0; s < S_N; ++s) { e[s] = __expf(lg[s] - mx); sum += e[s]; }
    float isum = 0.25f / sum;
#pragma unroll
    for (int s = 0; s < S_N; ++s) amha[s] += e[s] * isum;
  }

  float ageo[S_N];
  {
    const float nf = fmaxf(sqrtf(ffv), 1e-12f);
    float g[S_N];
#pragma unroll
    for (int s = 0; s < S_N; ++s) {
      float ns = fmaxf(sqrtf(ss_[s]), 1e-12f);
      float cs0 = fs_[s] / (nf * ns);
      cs0 = fminf(fmaxf(cs0, -1.0f + 1e-7f), 1.0f - 1e-7f);
      g[s] = __expf(-acosf(cs0) / t);
    }
    float mx = g[0];
#pragma unroll
    for (int s = 1; s < S_N; ++s) mx = fmaxf(mx, g[s]);
    float sum = 0;
#pragma unroll
    for (int s = 0; s < S_N; ++s) { ageo[s] = __expf(g[s] - mx); sum += ageo[s]; }
#pragma unroll
    for (int s = 0; s < S_N; ++s) ageo[s] /= sum;
  }

  float acay[S_N];
  {
    const float SQ2 = 1.41421356237309515f;
    const float Aff = 0.72f;
    const float Ass = 0.72f - 0.32f * SQ2;
    const float Afs = -(8.0f + 4.0f * SQ2) / 25.0f;
    float lg[S_N];
#pragma unroll
    for (int s = 0; s < S_N; ++s)
      lg[s] = (Aff * ffv + Ass * ss_[s] + Afs * fs_[s]) / t;
    float mx = lg[0];
#pragma unroll
    for (int s = 1; s < S_N; ++s) mx = fmaxf(mx, lg[s]);
    float sum = 0;
#pragma unroll
    for (int s = 0; s < S_N; ++s) { acay[s] = __expf(lg[s] - mx); sum += acay[s]; }
#pragma unroll
    for (int s = 0; s < S_N; ++s) acay[s] /= sum;
  }

  float w0 = attn_w[0], w1 = attn_w[1], w2 = attn_w[2];
  float wm = fmaxf(w0, fmaxf(w1, w2));
  float e0 = __expf(w0 - wm), e1 = __expf(w1 - wm), e2 = __expf(w2 - wm);
  float wsum = e0 + e1 + e2;
  w0 = e0 / wsum; w1 = e1 / wsum; w2 = e2 / wsum;

  float cb[S_N], csum = 0;
#pragma unroll
  for (int s = 0; s < S_N; ++s) {
    cb[s] = w0 * amha[s] + w1 * ageo[s] + w2 * acay[s];
    csum += cb[s];
  }
  float ic = 1.0f / csum;
  float cbn[S_N];
#pragma unroll
  for (int s = 0; s < S_N; ++s) cbn[s] = cb[s] * ic;
  if (lane == 0) {
#pragma unroll
    for (int s = 0; s < S_N; ++s) comb_out[(size_t)b * S_N + s] = cbn[s];
  }

  const floatx4 fz = {0.f, 0.f, 0.f, 0.f};
#pragma unroll
  for (int cj = 0; cj < 4; ++cj) {
    const int c0 = cj * 512 + lane * 8;
    floatx4 accA = fz, accB = fz;
#pragma unroll
    for (int s = 0; s < S_N; ++s) {
      const float* lp = logits + ((size_t)s * B_N + b) * C_N + c0;
      floatx4 lA = *(const floatx4*)lp;
      floatx4 lB = *(const floatx4*)(lp + 4);
      accA += lA * cbn[s];
      accB += lB * cbn[s];
    }
    float* op = out + (size_t)b * C_N + c0;
    *(floatx4*)op = accA;
    *(floatx4*)(op + 4) = accB;
  }
}

extern "C" void kernel_launch(void* const* d_in, const int* in_sizes, int n_in,
                              void* d_out, int out_size, void* d_ws, size_t ws_size,
                              hipStream_t stream) {
  const float* features = (const float*)d_in[0];
  const float* logits   = (const float*)d_in[1];
  const float* sf       = (const float*)d_in[2];
  const float* Wq       = (const float*)d_in[3];
  const float* bq       = (const float*)d_in[4];
  const float* Wk       = (const float*)d_in[5];
  const float* bk       = (const float*)d_in[6];
  const float* emb      = (const float*)d_in[9];
  const float* temp     = (const float*)d_in[10];
  const float* attn_w   = (const float*)d_in[11];

  float* out  = (float*)d_out;
  float* comb = out + (size_t)B_N * C_N;

  char* w = (char*)d_ws;
  short* fbf = (short*)(w);                    // 8192*512  bf16 =  8.39 MB
  short* Rbf = (short*)(w + 16777216);         // 8192*2048 bf16 = 33.55 MB
  short* WqT = (short*)(w + 50331648);         // 512*512   bf16 =  0.52 MB
  short* Wkb = (short*)(w + 50855936);         // 512*512   bf16 =  0.52 MB
  float* qtb = (float*)(w + 51380224);         // 8192*4    f32

  // 1. f->bf16 + WqT transpose + Wk->bf16
  k_prep<<<dim3(2144), dim3(256), 0, stream>>>(features, Wq, Wk, fbf, WqT, Wkb);
  // 2. merged: Q-GEMM (K=512) + qt epilogue + R-GEMM from LDS Q-tile (no Qbf)
  k_gemmQR<<<dim3(4, 128), dim3(256), 0, stream>>>(fbf, WqT, Wkb, Rbf, bq, qtb, bk);
  // 3. fused stats + attentions + fuse + logits mix
  k_fused<<<dim3(2048), dim3(256), 0, stream>>>(features, sf, emb, qtb, Rbf,
                                                temp, attn_w, logits, out, comb);
}